// Round 1
// baseline (984.181 us; speedup 1.0000x reference)
//
#include <hip/hip_runtime.h>
#include <hip/hip_bf16.h>

#define H 16
#define F_IN 58
#define NPB 16  // nodes per block in agg/transform kernels (256 threads / 16 lanes)

static inline size_t align256(size_t x) { return (x + 255) & ~(size_t)255; }

// ---------- dtype detection: int64 vs int32 edge_index ----------
__global__ void detect_kernel(const int* eidx32, int* flag) {
    __shared__ int any;
    if (threadIdx.x == 0) any = 0;
    __syncthreads();
    int nz = 0;
    for (int j = threadIdx.x; j < 1024; j += 256)
        nz |= (eidx32[2 * j + 1] != 0);
    if (nz) atomicOr(&any, 1);
    __syncthreads();
    if (threadIdx.x == 0) *flag = (any == 0) ? 1 : 0;  // all-zero odd words -> int64
}

__device__ inline int load_idx(const void* eidx, long i, int is64) {
    if (is64) return (int)((const long long*)eidx)[i];
    return ((const int*)eidx)[i];
}

// ---------- degree histogram ----------
__global__ void hist_kernel(const void* eidx, int E, const int* flag64, int* deg) {
    int is64 = *flag64;
    int stride = gridDim.x * blockDim.x;
    for (int i = blockIdx.x * blockDim.x + threadIdx.x; i < E; i += stride) {
        int d = load_idx(eidx, (long)E + i, is64);
        atomicAdd(&deg[d], 1);
    }
}

// ---------- dinv = rsqrt(deg + 1) (self loop) ----------
__global__ void dinv_kernel(const int* deg, float* dinv, int n) {
    int v = blockIdx.x * blockDim.x + threadIdx.x;
    if (v < n) dinv[v] = rsqrtf((float)(deg[v] + 1));
}

// ---------- scan: per-block sums ----------
__global__ void block_sum_kernel(const int* deg, int n, int* bsum) {
    __shared__ int tmp[256];
    int v = blockIdx.x * 256 + threadIdx.x;
    tmp[threadIdx.x] = (v < n) ? deg[v] : 0;
    __syncthreads();
    for (int off = 128; off > 0; off >>= 1) {
        if (threadIdx.x < off) tmp[threadIdx.x] += tmp[threadIdx.x + off];
        __syncthreads();
    }
    if (threadIdx.x == 0) bsum[blockIdx.x] = tmp[0];
}

// ---------- scan: exclusive scan of block sums (single block, nb <= 1024) ----------
__global__ void block_scan_kernel(const int* bsum, int nb, int* boff) {
    __shared__ int tmp[1024];
    int tid = threadIdx.x;
    int val = (tid < nb) ? bsum[tid] : 0;
    tmp[tid] = val;
    __syncthreads();
    for (int off = 1; off < 1024; off <<= 1) {
        int t = (tid >= off) ? tmp[tid - off] : 0;
        __syncthreads();
        tmp[tid] += t;
        __syncthreads();
    }
    if (tid < nb) boff[tid] = tmp[tid] - val;  // exclusive
}

// ---------- scan: local scan + write rowstart & cursor ----------
__global__ void local_scan_kernel(const int* deg, int n, const int* boff,
                                  int* rowstart, int* cursor, int E) {
    __shared__ int tmp[256];
    int tid = threadIdx.x;
    int v = blockIdx.x * 256 + tid;
    int val = (v < n) ? deg[v] : 0;
    tmp[tid] = val;
    __syncthreads();
    for (int off = 1; off < 256; off <<= 1) {
        int t = (tid >= off) ? tmp[tid - off] : 0;
        __syncthreads();
        tmp[tid] += t;
        __syncthreads();
    }
    if (v < n) {
        int start = boff[blockIdx.x] + tmp[tid] - val;
        rowstart[v] = start;
        cursor[v] = start;
    }
    if (v == 0) rowstart[n] = E;
}

// ---------- scatter edges into CSR slots: (src, norm) pairs ----------
__global__ void scatter_kernel(const void* eidx, int E, const int* flag64,
                               const float* dinv, int* cursor, float2* ed) {
    int is64 = *flag64;
    int stride = gridDim.x * blockDim.x;
    for (int i = blockIdx.x * blockDim.x + threadIdx.x; i < E; i += stride) {
        int s = load_idx(eidx, i, is64);
        int d = load_idx(eidx, (long)E + i, is64);
        int pos = atomicAdd(&cursor[d], 1);
        ed[pos] = make_float2(__int_as_float(s), dinv[s] * dinv[d]);
    }
}

// ---------- layer 0 dense transform: hw0 = x @ W0 ----------
__global__ void t0_kernel(const float* __restrict__ x, const float* __restrict__ W0,
                          float* __restrict__ hw, int n) {
    __shared__ float Wl[F_IN * H];
    int tid = threadIdx.x;
    for (int j = tid; j < F_IN * H; j += 256) Wl[j] = W0[j];
    __syncthreads();
    int g = tid >> 4, f = tid & 15;
    int v = blockIdx.x * NPB + g;
    if (v >= n) return;
    const float* xr = x + (long)v * F_IN;
    float acc = 0.f;
#pragma unroll
    for (int k = 0; k < F_IN; ++k) acc += xr[k] * Wl[k * H + f];
    hw[v * H + f] = acc;
}

// ---------- aggregation (+ bias, relu, jk-max, fused next-layer transform) ----------
__global__ void agg_kernel(const float2* __restrict__ ed, const int* __restrict__ rowstart,
                           const float* __restrict__ dinv, const float* __restrict__ hw,
                           const float* __restrict__ bias, const float* __restrict__ Wnext,
                           float* __restrict__ jk, float* __restrict__ hw_next,
                           int n, int first, int has_next) {
    __shared__ float Wl[H * H];
    int tid = threadIdx.x;
    if (has_next) Wl[tid] = Wnext[tid];  // 256 threads == 16x16
    __syncthreads();
    int g = tid >> 4, f = tid & 15;
    int v = blockIdx.x * NPB + g;
    if (v >= n) return;
    float dv = dinv[v];
    int s = rowstart[v], e = rowstart[v + 1];
    float acc = dv * dv * hw[v * H + f];  // self-loop: norm = dinv[v]^2
    for (int i = s; i < e; i += 4) {
        float2 q0 = ed[i];
        float2 q1 = (i + 1 < e) ? ed[i + 1] : make_float2(0.f, 0.f);
        float2 q2 = (i + 2 < e) ? ed[i + 2] : make_float2(0.f, 0.f);
        float2 q3 = (i + 3 < e) ? ed[i + 3] : make_float2(0.f, 0.f);
        acc += q0.y * hw[__float_as_int(q0.x) * H + f];
        acc += q1.y * hw[__float_as_int(q1.x) * H + f];
        acc += q2.y * hw[__float_as_int(q2.x) * H + f];
        acc += q3.y * hw[__float_as_int(q3.x) * H + f];
    }
    float val = fmaxf(acc + bias[f], 0.f);
    float j = first ? val : fmaxf(jk[v * H + f], val);
    jk[v * H + f] = j;
    if (has_next) {
        float acc2 = 0.f;
#pragma unroll
        for (int k = 0; k < H; ++k) {
            float hk = __shfl(val, k, 16);
            acc2 += hk * Wl[k * H + f];
        }
        hw_next[v * H + f] = acc2;
    }
}

// ---------- final FC: out = jk @ fc_w + fc_b ----------
__global__ void fc_kernel(const float* __restrict__ jk, const float* __restrict__ fc_w,
                          const float* __restrict__ fc_b, float* __restrict__ out, int n) {
    __shared__ float w[H];
    __shared__ float b0;
    if (threadIdx.x < H) w[threadIdx.x] = fc_w[threadIdx.x];
    if (threadIdx.x == 0) b0 = fc_b[0];
    __syncthreads();
    int v = blockIdx.x * 256 + threadIdx.x;
    if (v >= n) return;
    const float4* r = (const float4*)(jk + (long)v * H);
    float4 a = r[0], b = r[1], c = r[2], d = r[3];
    float sum = a.x * w[0] + a.y * w[1] + a.z * w[2] + a.w * w[3]
              + b.x * w[4] + b.y * w[5] + b.z * w[6] + b.w * w[7]
              + c.x * w[8] + c.y * w[9] + c.z * w[10] + c.w * w[11]
              + d.x * w[12] + d.y * w[13] + d.z * w[14] + d.w * w[15];
    out[v] = sum + b0;
}

extern "C" void kernel_launch(void* const* d_in, const int* in_sizes, int n_in,
                              void* d_out, int out_size, void* d_ws, size_t ws_size,
                              hipStream_t stream) {
    const float* x    = (const float*)d_in[0];
    const void*  eidx = d_in[1];
    const float* W0   = (const float*)d_in[2];
    const float* Ws   = (const float*)d_in[3];
    const float* bs   = (const float*)d_in[4];
    const float* fc_w = (const float*)d_in[5];
    const float* fc_b = (const float*)d_in[6];

    int n = in_sizes[0] / F_IN;        // 100000
    int E = in_sizes[1] / 2;           // 3200000
    int L = in_sizes[4] / H;           // 10

    // workspace carve-up
    char* w = (char*)d_ws;
    size_t off = 0;
    int* deg      = (int*)(w + off); off += align256((size_t)n * 4);
    int* rowstart = (int*)(w + off); off += align256((size_t)(n + 1) * 4);
    int* cursor   = (int*)(w + off); off += align256((size_t)n * 4);
    float* dinv   = (float*)(w + off); off += align256((size_t)n * 4);
    int* bsum     = (int*)(w + off); off += align256(1024 * 4);
    int* boff     = (int*)(w + off); off += align256(1024 * 4);
    int* flag64   = (int*)(w + off); off += align256(256);
    float2* ed    = (float2*)(w + off); off += align256((size_t)E * 8);
    float* hwA    = (float*)(w + off); off += align256((size_t)n * H * 4);
    float* hwB    = (float*)(w + off); off += align256((size_t)n * H * 4);
    float* jk     = (float*)(w + off); off += align256((size_t)n * H * 4);

    int NB = (n + 255) / 256;          // 391 (<=1024 for the single-block scan)

    hipMemsetAsync(deg, 0, (size_t)n * 4, stream);
    detect_kernel<<<1, 256, 0, stream>>>((const int*)eidx, flag64);
    hist_kernel<<<2048, 256, 0, stream>>>(eidx, E, flag64, deg);
    dinv_kernel<<<NB, 256, 0, stream>>>(deg, dinv, n);
    block_sum_kernel<<<NB, 256, 0, stream>>>(deg, n, bsum);
    block_scan_kernel<<<1, 1024, 0, stream>>>(bsum, NB, boff);
    local_scan_kernel<<<NB, 256, 0, stream>>>(deg, n, boff, rowstart, cursor, E);
    scatter_kernel<<<2048, 256, 0, stream>>>(eidx, E, flag64, dinv, cursor, ed);

    int ngrid = (n + NPB - 1) / NPB;   // 6250
    t0_kernel<<<ngrid, 256, 0, stream>>>(x, W0, hwA, n);

    float* cur = hwA;
    float* nxt = hwB;
    for (int l = 0; l < L; ++l) {
        const float* bias  = bs + (size_t)l * H;
        const float* Wnext = (l < L - 1) ? (Ws + (size_t)l * H * H) : nullptr;
        agg_kernel<<<ngrid, 256, 0, stream>>>(ed, rowstart, dinv, cur, bias, Wnext,
                                              jk, nxt, n, (l == 0) ? 1 : 0,
                                              (l < L - 1) ? 1 : 0);
        float* t = cur; cur = nxt; nxt = t;
    }

    fc_kernel<<<NB, 256, 0, stream>>>(jk, fc_w, fc_b, (float*)d_out, n);
}

// Round 2
// 690.704 us; speedup vs baseline: 1.4249x; 1.4249x over previous
//
#include <hip/hip_runtime.h>
#include <hip/hip_bf16.h>

#define H 16
#define F_IN 58
#define NPB 16  // nodes per block in agg/transform kernels (256 threads / 16 lanes)

static inline size_t align256(size_t x) { return (x + 255) & ~(size_t)255; }

// ---------- dtype detection: int64 vs int32 edge_index ----------
__global__ void detect_kernel(const int* eidx32, int* flag) {
    __shared__ int any;
    if (threadIdx.x == 0) any = 0;
    __syncthreads();
    int nz = 0;
    for (int j = threadIdx.x; j < 1024; j += 256)
        nz |= (eidx32[2 * j + 1] != 0);
    if (nz) atomicOr(&any, 1);
    __syncthreads();
    if (threadIdx.x == 0) *flag = (any == 0) ? 1 : 0;  // all-zero odd words -> int64
}

__device__ inline int load_idx(const void* eidx, long i, int is64) {
    if (is64) return (int)((const long long*)eidx)[i];
    return ((const int*)eidx)[i];
}

// ---------- degree histogram ----------
__global__ void hist_kernel(const void* eidx, int E, const int* flag64, int* deg) {
    int is64 = *flag64;
    int stride = gridDim.x * blockDim.x;
    for (int i = blockIdx.x * blockDim.x + threadIdx.x; i < E; i += stride) {
        int d = load_idx(eidx, (long)E + i, is64);
        atomicAdd(&deg[d], 1);
    }
}

// ---------- dinv = rsqrt(deg + 1) (self loop) ----------
__global__ void dinv_kernel(const int* deg, float* dinv, int n) {
    int v = blockIdx.x * blockDim.x + threadIdx.x;
    if (v < n) dinv[v] = rsqrtf((float)(deg[v] + 1));
}

// ---------- scan: per-block sums ----------
__global__ void block_sum_kernel(const int* deg, int n, int* bsum) {
    __shared__ int tmp[256];
    int v = blockIdx.x * 256 + threadIdx.x;
    tmp[threadIdx.x] = (v < n) ? deg[v] : 0;
    __syncthreads();
    for (int off = 128; off > 0; off >>= 1) {
        if (threadIdx.x < off) tmp[threadIdx.x] += tmp[threadIdx.x + off];
        __syncthreads();
    }
    if (threadIdx.x == 0) bsum[blockIdx.x] = tmp[0];
}

// ---------- scan: exclusive scan of block sums (single block, nb <= 1024) ----------
__global__ void block_scan_kernel(const int* bsum, int nb, int* boff) {
    __shared__ int tmp[1024];
    int tid = threadIdx.x;
    int val = (tid < nb) ? bsum[tid] : 0;
    tmp[tid] = val;
    __syncthreads();
    for (int off = 1; off < 1024; off <<= 1) {
        int t = (tid >= off) ? tmp[tid - off] : 0;
        __syncthreads();
        tmp[tid] += t;
        __syncthreads();
    }
    if (tid < nb) boff[tid] = tmp[tid] - val;  // exclusive
}

// ---------- scan: local scan + write rowstart ----------
__global__ void local_scan_kernel(const int* deg, int n, const int* boff,
                                  int* rowstart, int E) {
    __shared__ int tmp[256];
    int tid = threadIdx.x;
    int v = blockIdx.x * 256 + tid;
    int val = (v < n) ? deg[v] : 0;
    tmp[tid] = val;
    __syncthreads();
    for (int off = 1; off < 256; off <<= 1) {
        int t = (tid >= off) ? tmp[tid - off] : 0;
        __syncthreads();
        tmp[tid] += t;
        __syncthreads();
    }
    if (v < n) rowstart[v] = boff[blockIdx.x] + tmp[tid] - val;
    if (v == 0) rowstart[n] = E;
}

// ---------- init per-bucket global cursors to bucket base ----------
__global__ void binit_kernel(const int* rowstart, int n, int* gcur) {
    int B = (n + 255) >> 8;
    int b = blockIdx.x * blockDim.x + threadIdx.x;
    if (b < B) gcur[b] = rowstart[b << 8];
}

// ---------- pass A: coarse bucket staging (coalesced per-bucket runs) ----------
__global__ void stage_kernel(const void* eidx, int E, const int* flag64,
                             int n, int* gcur, unsigned* staging) {
    __shared__ int hist[512];
    __shared__ int base[512];
    int is64 = *flag64;
    int B = (n + 255) >> 8;
    int tid = threadIdx.x;
    for (int j = tid; j < B; j += 256) hist[j] = 0;
    __syncthreads();
    int chunk = (E + gridDim.x - 1) / gridDim.x;
    int s0 = blockIdx.x * chunk;
    int s1 = min(E, s0 + chunk);
    for (int i = s0 + tid; i < s1; i += 256) {
        int d = load_idx(eidx, (long)E + i, is64);
        atomicAdd(&hist[d >> 8], 1);
    }
    __syncthreads();
    for (int j = tid; j < B; j += 256) {
        int c = hist[j];
        base[j] = c ? atomicAdd(&gcur[j], c) : 0;
        hist[j] = 0;
    }
    __syncthreads();
    for (int i = s0 + tid; i < s1; i += 256) {
        int s = load_idx(eidx, i, is64);
        int d = load_idx(eidx, (long)E + i, is64);
        int b = d >> 8;
        int loc = atomicAdd(&hist[b], 1);
        staging[base[b] + loc] = (unsigned)s | ((unsigned)(d & 255) << 17);
    }
}

// ---------- pass B: fine scatter within bucket (L2-hot 32KB window) ----------
__global__ void fine_kernel(const unsigned* __restrict__ staging,
                            const int* __restrict__ rowstart, int n,
                            int* __restrict__ ed) {
    __shared__ int lcur[256];
    int tid = threadIdx.x;
    lcur[tid] = 0;
    __syncthreads();
    int node0 = blockIdx.x << 8;
    int start = rowstart[node0];
    int nend = min(node0 + 256, n);
    int cnt = rowstart[nend] - start;
    for (int i = tid; i < cnt; i += 256) {
        unsigned w = staging[start + i];
        int src = (int)(w & 0x1FFFFu);
        int ld = (int)(w >> 17);
        int pos = rowstart[node0 + ld] + atomicAdd(&lcur[ld], 1);
        ed[pos] = src;
    }
}

// ---------- layer 0 dense transform: hw0 = dinv * (x @ W0) ----------
__global__ void t0_kernel(const float* __restrict__ x, const float* __restrict__ W0,
                          const float* __restrict__ dinv, float* __restrict__ hw, int n) {
    __shared__ float Wl[F_IN * H];
    int tid = threadIdx.x;
    for (int j = tid; j < F_IN * H; j += 256) Wl[j] = W0[j];
    __syncthreads();
    int g = tid >> 4, f = tid & 15;
    int v = blockIdx.x * NPB + g;
    if (v >= n) return;
    const float* xr = x + (long)v * F_IN;
    float acc = 0.f;
#pragma unroll
    for (int k = 0; k < F_IN; ++k) acc += xr[k] * Wl[k * H + f];
    hw[v * H + f] = acc * dinv[v];
}

// ---------- aggregation (+ bias, relu, jk-max, fused next-layer transform) ----------
// hw holds dinv-scaled transformed features; agg = dinv[v] * (sum_src hw[src] + hw[v])
__global__ void agg_kernel(const int* __restrict__ ed, const int* __restrict__ rowstart,
                           const float* __restrict__ dinv, const float* __restrict__ hw,
                           const float* __restrict__ bias, const float* __restrict__ Wnext,
                           float* __restrict__ jk, float* __restrict__ hw_next,
                           int n, int first, int has_next) {
    __shared__ float Wl[H * H];
    int tid = threadIdx.x;
    if (has_next) Wl[tid] = Wnext[tid];  // 256 threads == 16x16
    __syncthreads();
    int g = tid >> 4, f = tid & 15;
    int v = blockIdx.x * NPB + g;
    if (v >= n) return;
    float dv = dinv[v];
    int s = rowstart[v], e = rowstart[v + 1];
    float acc = hw[v * H + f];  // self-loop term (dinv folded later via *dv)
    float a0 = 0.f, a1 = 0.f, a2 = 0.f, a3 = 0.f;
    int i = s;
    for (; i + 8 <= e; i += 8) {
        int t0 = ed[i],     t1 = ed[i + 1], t2 = ed[i + 2], t3 = ed[i + 3];
        int t4 = ed[i + 4], t5 = ed[i + 5], t6 = ed[i + 6], t7 = ed[i + 7];
        a0 += hw[t0 * H + f];
        a1 += hw[t1 * H + f];
        a2 += hw[t2 * H + f];
        a3 += hw[t3 * H + f];
        a0 += hw[t4 * H + f];
        a1 += hw[t5 * H + f];
        a2 += hw[t6 * H + f];
        a3 += hw[t7 * H + f];
    }
    for (; i < e; ++i) a0 += hw[ed[i] * H + f];
    acc += (a0 + a1) + (a2 + a3);
    float val = fmaxf(acc * dv + bias[f], 0.f);
    float j = first ? val : fmaxf(jk[v * H + f], val);
    jk[v * H + f] = j;
    if (has_next) {
        float acc2 = 0.f;
#pragma unroll
        for (int k = 0; k < H; ++k) {
            float hk = __shfl(val, k, 16);
            acc2 += hk * Wl[k * H + f];
        }
        hw_next[v * H + f] = acc2 * dv;
    }
}

// ---------- final FC: out = jk @ fc_w + fc_b ----------
__global__ void fc_kernel(const float* __restrict__ jk, const float* __restrict__ fc_w,
                          const float* __restrict__ fc_b, float* __restrict__ out, int n) {
    __shared__ float w[H];
    __shared__ float b0;
    if (threadIdx.x < H) w[threadIdx.x] = fc_w[threadIdx.x];
    if (threadIdx.x == 0) b0 = fc_b[0];
    __syncthreads();
    int v = blockIdx.x * 256 + threadIdx.x;
    if (v >= n) return;
    const float4* r = (const float4*)(jk + (long)v * H);
    float4 a = r[0], b = r[1], c = r[2], d = r[3];
    float sum = a.x * w[0] + a.y * w[1] + a.z * w[2] + a.w * w[3]
              + b.x * w[4] + b.y * w[5] + b.z * w[6] + b.w * w[7]
              + c.x * w[8] + c.y * w[9] + c.z * w[10] + c.w * w[11]
              + d.x * w[12] + d.y * w[13] + d.z * w[14] + d.w * w[15];
    out[v] = sum + b0;
}

extern "C" void kernel_launch(void* const* d_in, const int* in_sizes, int n_in,
                              void* d_out, int out_size, void* d_ws, size_t ws_size,
                              hipStream_t stream) {
    const float* x    = (const float*)d_in[0];
    const void*  eidx = d_in[1];
    const float* W0   = (const float*)d_in[2];
    const float* Ws   = (const float*)d_in[3];
    const float* bs   = (const float*)d_in[4];
    const float* fc_w = (const float*)d_in[5];
    const float* fc_b = (const float*)d_in[6];

    int n = in_sizes[0] / F_IN;        // 100000
    int E = in_sizes[1] / 2;           // 3200000
    int L = in_sizes[4] / H;           // 10

    // workspace carve-up
    char* w = (char*)d_ws;
    size_t off = 0;
    int* deg        = (int*)(w + off); off += align256((size_t)n * 4);
    int* rowstart   = (int*)(w + off); off += align256((size_t)(n + 1) * 4);
    float* dinv     = (float*)(w + off); off += align256((size_t)n * 4);
    int* bsum       = (int*)(w + off); off += align256(1024 * 4);
    int* boff       = (int*)(w + off); off += align256(1024 * 4);
    int* gcur       = (int*)(w + off); off += align256(512 * 4);
    int* flag64     = (int*)(w + off); off += align256(256);
    unsigned* stg   = (unsigned*)(w + off); off += align256((size_t)E * 4);
    int* ed         = (int*)(w + off); off += align256((size_t)E * 4);
    float* hwA      = (float*)(w + off); off += align256((size_t)n * H * 4);
    float* hwB      = (float*)(w + off); off += align256((size_t)n * H * 4);
    float* jk       = (float*)(w + off); off += align256((size_t)n * H * 4);

    int NB = (n + 255) / 256;          // 391 blocks of 256 (also = bucket count)

    hipMemsetAsync(deg, 0, (size_t)n * 4, stream);
    detect_kernel<<<1, 256, 0, stream>>>((const int*)eidx, flag64);
    hist_kernel<<<2048, 256, 0, stream>>>(eidx, E, flag64, deg);
    dinv_kernel<<<NB, 256, 0, stream>>>(deg, dinv, n);
    block_sum_kernel<<<NB, 256, 0, stream>>>(deg, n, bsum);
    block_scan_kernel<<<1, 1024, 0, stream>>>(bsum, NB, boff);
    local_scan_kernel<<<NB, 256, 0, stream>>>(deg, n, boff, rowstart, E);
    binit_kernel<<<2, 256, 0, stream>>>(rowstart, n, gcur);
    stage_kernel<<<512, 256, 0, stream>>>(eidx, E, flag64, n, gcur, stg);
    fine_kernel<<<NB, 256, 0, stream>>>(stg, rowstart, n, ed);

    int ngrid = (n + NPB - 1) / NPB;   // 6250
    t0_kernel<<<ngrid, 256, 0, stream>>>(x, W0, dinv, hwA, n);

    float* cur = hwA;
    float* nxt = hwB;
    for (int l = 0; l < L; ++l) {
        const float* bias  = bs + (size_t)l * H;
        const float* Wnext = (l < L - 1) ? (Ws + (size_t)l * H * H) : nullptr;
        agg_kernel<<<ngrid, 256, 0, stream>>>(ed, rowstart, dinv, cur, bias, Wnext,
                                              jk, nxt, n, (l == 0) ? 1 : 0,
                                              (l < L - 1) ? 1 : 0);
        float* t = cur; cur = nxt; nxt = t;
    }

    fc_kernel<<<NB, 256, 0, stream>>>(jk, fc_w, fc_b, (float*)d_out, n);
}

// Round 3
// 468.398 us; speedup vs baseline: 2.1012x; 1.4746x over previous
//
#include <hip/hip_runtime.h>
#include <hip/hip_bf16.h>

#define H 16
#define F_IN 58
#define NPB 16   // nodes per block in agg/transform kernels (256 threads / 16 lanes)

static inline size_t align256(size_t x) { return (x + 255) & ~(size_t)255; }

__device__ inline float bf2f(__hip_bfloat16 h) { return __bfloat162float(h); }

// ---------- dtype detection: int64 vs int32 edge_index ----------
__global__ void detect_kernel(const int* eidx32, int* flag) {
    __shared__ int any;
    if (threadIdx.x == 0) any = 0;
    __syncthreads();
    int nz = 0;
    for (int j = threadIdx.x; j < 1024; j += 256)
        nz |= (eidx32[2 * j + 1] != 0);
    if (nz) atomicOr(&any, 1);
    __syncthreads();
    if (threadIdx.x == 0) *flag = (any == 0) ? 1 : 0;  // all-zero odd words -> int64
}

__device__ inline int load_idx(const void* eidx, long i, int is64) {
    if (is64) return (int)((const long long*)eidx)[i];
    return ((const int*)eidx)[i];
}

// ---------- bucket counts (391 bins) via LDS histogram ----------
__global__ void bcount_kernel(const void* eidx, int E, const int* flag64,
                              int n, int* bucketcnt) {
    __shared__ int hist[512];
    int is64 = *flag64;
    int B = (n + 255) >> 8;
    int tid = threadIdx.x;
    for (int j = tid; j < B; j += 256) hist[j] = 0;
    __syncthreads();
    int stride = gridDim.x * blockDim.x;
    for (int i = blockIdx.x * blockDim.x + tid; i < E; i += stride) {
        int d = load_idx(eidx, (long)E + i, is64);
        atomicAdd(&hist[d >> 8], 1);
    }
    __syncthreads();
    for (int j = tid; j < B; j += 256)
        if (hist[j]) atomicAdd(&bucketcnt[j], hist[j]);
}

// ---------- exclusive scan of bucket counts (single block) ----------
__global__ void bscan_kernel(const int* bucketcnt, int B, int E,
                             int* gcur, int* bucketbase) {
    __shared__ int tmp[512];
    int tid = threadIdx.x;
    int val = (tid < B) ? bucketcnt[tid] : 0;
    tmp[tid] = val;
    __syncthreads();
    for (int off = 1; off < 512; off <<= 1) {
        int t = (tid >= off) ? tmp[tid - off] : 0;
        __syncthreads();
        tmp[tid] += t;
        __syncthreads();
    }
    if (tid < B) {
        int ex = tmp[tid] - val;
        gcur[tid] = ex;
        bucketbase[tid] = ex;
    }
    if (tid == 0) bucketbase[B] = E;
}

// ---------- pass A: coarse bucket staging (coalesced per-bucket runs) ----------
__global__ void stage_kernel(const void* eidx, int E, const int* flag64,
                             int n, int* gcur, unsigned* staging) {
    __shared__ int hist[512];
    __shared__ int base[512];
    int is64 = *flag64;
    int B = (n + 255) >> 8;
    int tid = threadIdx.x;
    for (int j = tid; j < B; j += 256) hist[j] = 0;
    __syncthreads();
    int chunk = (E + gridDim.x - 1) / gridDim.x;
    int s0 = blockIdx.x * chunk;
    int s1 = min(E, s0 + chunk);
    for (int i = s0 + tid; i < s1; i += 256) {
        int d = load_idx(eidx, (long)E + i, is64);
        atomicAdd(&hist[d >> 8], 1);
    }
    __syncthreads();
    for (int j = tid; j < B; j += 256) {
        int c = hist[j];
        base[j] = c ? atomicAdd(&gcur[j], c) : 0;
        hist[j] = 0;
    }
    __syncthreads();
    for (int i = s0 + tid; i < s1; i += 256) {
        int s = load_idx(eidx, i, is64);
        int d = load_idx(eidx, (long)E + i, is64);
        int b = d >> 8;
        int loc = atomicAdd(&hist[b], 1);
        staging[base[b] + loc] = (unsigned)s | ((unsigned)(d & 255) << 17);
    }
}

// ---------- pass B: per-bucket local hist + scan -> rowstart/dinv, then scatter ----------
__global__ void fine_kernel(const unsigned* __restrict__ staging,
                            const int* __restrict__ bucketbase, int n, int E,
                            int* __restrict__ ed, int* __restrict__ rowstart,
                            float* __restrict__ dinv) {
    __shared__ int lcnt[256];
    __shared__ int lofs[256];
    __shared__ int lcur[256];
    int tid = threadIdx.x;
    int b = blockIdx.x;
    int node0 = b << 8;
    int start = bucketbase[b], end = bucketbase[b + 1];
    int cnt = end - start;
    lcnt[tid] = 0;
    lcur[tid] = 0;
    __syncthreads();
    for (int i = tid; i < cnt; i += 256) {
        unsigned w = staging[start + i];
        atomicAdd(&lcnt[w >> 17], 1);
    }
    __syncthreads();
    int val = lcnt[tid];
    lofs[tid] = val;
    __syncthreads();
    for (int off = 1; off < 256; off <<= 1) {
        int t = (tid >= off) ? lofs[tid - off] : 0;
        __syncthreads();
        lofs[tid] += t;
        __syncthreads();
    }
    int ex = lofs[tid] - val;
    __syncthreads();
    lofs[tid] = ex;
    __syncthreads();
    int node = node0 + tid;
    if (node < n) {
        rowstart[node] = start + ex;
        dinv[node] = rsqrtf((float)(val + 1));
    }
    if (node == 0) rowstart[n] = E;
    for (int i = tid; i < cnt; i += 256) {
        unsigned w = staging[start + i];
        int ld = (int)(w >> 17);
        int pos = start + lofs[ld] + atomicAdd(&lcur[ld], 1);
        ed[pos] = (int)(w & 0x1FFFFu);
    }
}

// ---------- layer 0 dense transform: hw0 = bf16(dinv * (x @ W0)) ----------
__global__ void t0_kernel(const float* __restrict__ x, const float* __restrict__ W0,
                          const float* __restrict__ dinv,
                          __hip_bfloat16* __restrict__ hw, int n) {
    __shared__ float Wl[F_IN * H];
    int tid = threadIdx.x;
    for (int j = tid; j < F_IN * H; j += 256) Wl[j] = W0[j];
    __syncthreads();
    int g = tid >> 4, f = tid & 15;
    int v = blockIdx.x * NPB + g;
    if (v >= n) return;
    const float* xr = x + (long)v * F_IN;
    float acc = 0.f;
#pragma unroll
    for (int k = 0; k < F_IN; ++k) acc += xr[k] * Wl[k * H + f];
    hw[v * H + f] = __float2bfloat16(acc * dinv[v]);
}

// ---------- aggregation (+ bias, relu, jk-max, fused next-layer transform) ----------
// hw holds dinv-scaled transformed features (bf16); agg = dinv[v]*(sum_src hw[src] + hw[v])
__global__ void agg_kernel(const int* __restrict__ ed, const int* __restrict__ rowstart,
                           const float* __restrict__ dinv,
                           const __hip_bfloat16* __restrict__ hw,
                           const float* __restrict__ bias, const float* __restrict__ Wnext,
                           float* __restrict__ jk, __hip_bfloat16* __restrict__ hw_next,
                           int n, int first, int has_next) {
    __shared__ float Wl[H * H];
    int tid = threadIdx.x;
    if (has_next) Wl[tid] = Wnext[tid];  // 256 threads == 16x16
    __syncthreads();
    int g = tid >> 4, f = tid & 15;
    int v = blockIdx.x * NPB + g;
    if (v >= n) return;
    float dv = dinv[v];
    int s = rowstart[v], e = rowstart[v + 1];
    float acc = bf2f(hw[v * H + f]);  // self-loop term
    float a0 = 0.f, a1 = 0.f, a2 = 0.f, a3 = 0.f;
    int i = s;
    for (; i + 8 <= e; i += 8) {
        int t0 = ed[i],     t1 = ed[i + 1], t2 = ed[i + 2], t3 = ed[i + 3];
        int t4 = ed[i + 4], t5 = ed[i + 5], t6 = ed[i + 6], t7 = ed[i + 7];
        a0 += bf2f(hw[t0 * H + f]);
        a1 += bf2f(hw[t1 * H + f]);
        a2 += bf2f(hw[t2 * H + f]);
        a3 += bf2f(hw[t3 * H + f]);
        a0 += bf2f(hw[t4 * H + f]);
        a1 += bf2f(hw[t5 * H + f]);
        a2 += bf2f(hw[t6 * H + f]);
        a3 += bf2f(hw[t7 * H + f]);
    }
    for (; i < e; ++i) a0 += bf2f(hw[ed[i] * H + f]);
    acc += (a0 + a1) + (a2 + a3);
    float val = fmaxf(acc * dv + bias[f], 0.f);
    float j = first ? val : fmaxf(jk[v * H + f], val);
    jk[v * H + f] = j;
    if (has_next) {
        float acc2 = 0.f;
#pragma unroll
        for (int k = 0; k < H; ++k) {
            float hk = __shfl(val, k, 16);
            acc2 += hk * Wl[k * H + f];
        }
        hw_next[v * H + f] = __float2bfloat16(acc2 * dv);
    }
}

// ---------- final FC: out = jk @ fc_w + fc_b ----------
__global__ void fc_kernel(const float* __restrict__ jk, const float* __restrict__ fc_w,
                          const float* __restrict__ fc_b, float* __restrict__ out, int n) {
    __shared__ float w[H];
    __shared__ float b0;
    if (threadIdx.x < H) w[threadIdx.x] = fc_w[threadIdx.x];
    if (threadIdx.x == 0) b0 = fc_b[0];
    __syncthreads();
    int v = blockIdx.x * 256 + threadIdx.x;
    if (v >= n) return;
    const float4* r = (const float4*)(jk + (long)v * H);
    float4 a = r[0], b = r[1], c = r[2], d = r[3];
    float sum = a.x * w[0] + a.y * w[1] + a.z * w[2] + a.w * w[3]
              + b.x * w[4] + b.y * w[5] + b.z * w[6] + b.w * w[7]
              + c.x * w[8] + c.y * w[9] + c.z * w[10] + c.w * w[11]
              + d.x * w[12] + d.y * w[13] + d.z * w[14] + d.w * w[15];
    out[v] = sum + b0;
}

extern "C" void kernel_launch(void* const* d_in, const int* in_sizes, int n_in,
                              void* d_out, int out_size, void* d_ws, size_t ws_size,
                              hipStream_t stream) {
    const float* x    = (const float*)d_in[0];
    const void*  eidx = d_in[1];
    const float* W0   = (const float*)d_in[2];
    const float* Ws   = (const float*)d_in[3];
    const float* bs   = (const float*)d_in[4];
    const float* fc_w = (const float*)d_in[5];
    const float* fc_b = (const float*)d_in[6];

    int n = in_sizes[0] / F_IN;        // 100000
    int E = in_sizes[1] / 2;           // 3200000
    int L = in_sizes[4] / H;           // 10

    // workspace carve-up
    char* w = (char*)d_ws;
    size_t off = 0;
    int* rowstart    = (int*)(w + off); off += align256((size_t)(n + 1) * 4);
    float* dinv      = (float*)(w + off); off += align256((size_t)n * 4);
    int* bucketcnt   = (int*)(w + off); off += align256(512 * 4);
    int* bucketbase  = (int*)(w + off); off += align256(513 * 4);
    int* gcur        = (int*)(w + off); off += align256(512 * 4);
    int* flag64      = (int*)(w + off); off += align256(256);
    unsigned* stg    = (unsigned*)(w + off); off += align256((size_t)E * 4);
    int* ed          = (int*)(w + off); off += align256((size_t)E * 4);
    __hip_bfloat16* hwA = (__hip_bfloat16*)(w + off); off += align256((size_t)n * H * 2);
    __hip_bfloat16* hwB = (__hip_bfloat16*)(w + off); off += align256((size_t)n * H * 2);
    float* jk        = (float*)(w + off); off += align256((size_t)n * H * 4);

    int NB = (n + 255) / 256;          // 391 blocks of 256 (also = bucket count)

    hipMemsetAsync(bucketcnt, 0, 512 * 4, stream);
    detect_kernel<<<1, 256, 0, stream>>>((const int*)eidx, flag64);
    bcount_kernel<<<512, 256, 0, stream>>>(eidx, E, flag64, n, bucketcnt);
    bscan_kernel<<<1, 512, 0, stream>>>(bucketcnt, NB, E, gcur, bucketbase);
    stage_kernel<<<512, 256, 0, stream>>>(eidx, E, flag64, n, gcur, stg);
    fine_kernel<<<NB, 256, 0, stream>>>(stg, bucketbase, n, E, ed, rowstart, dinv);

    int ngrid = (n + NPB - 1) / NPB;   // 6250
    t0_kernel<<<ngrid, 256, 0, stream>>>(x, W0, dinv, hwA, n);

    __hip_bfloat16* cur = hwA;
    __hip_bfloat16* nxt = hwB;
    for (int l = 0; l < L; ++l) {
        const float* bias  = bs + (size_t)l * H;
        const float* Wnext = (l < L - 1) ? (Ws + (size_t)l * H * H) : nullptr;
        agg_kernel<<<ngrid, 256, 0, stream>>>(ed, rowstart, dinv, cur, bias, Wnext,
                                              jk, nxt, n, (l == 0) ? 1 : 0,
                                              (l < L - 1) ? 1 : 0);
        __hip_bfloat16* t = cur; cur = nxt; nxt = t;
    }

    fc_kernel<<<NB, 256, 0, stream>>>(jk, fc_w, fc_b, (float*)d_out, n);
}